// Round 5
// baseline (53.577 us; speedup 1.0000x reference)
//
#include <hip/hip_runtime.h>
#include <hip/hip_bf16.h>

// MMD loss, MI355X. Round 5:
//  - gram: LDS-staged double-buffered tiles via global_load_lds (16B) to
//    halve L2 traffic (round-4 structure had 2x re-load redundancy across
//    the 2x2 wave grid). Fragment-major layout is linear per 1KB fragment,
//    exactly matching global_load_lds's uniform-base + lane*16 semantics.
//  - everything else (no atomics, fragment-major prep, symmetry, 3-mode
//    fused gram, block-partial stores + single reduce) carried from R4.
//
// ws layout: [sfb fragmajor | tfb fragmajor | x2s | x2t | wv | block_out]

typedef short bf16x8 __attribute__((ext_vector_type(8)));
typedef float f32x4 __attribute__((ext_vector_type(4)));

#define D 256  // feature dim (validated from in_sizes at launch)

static __device__ __forceinline__ unsigned short f32_to_bf16(float f) {
    unsigned int x = __float_as_uint(f);
    unsigned int r = (x + 0x7FFFu + ((x >> 16) & 1u)) >> 16;  // RNE
    return (unsigned short)r;
}

// Fragment-major layout: elem (row r, feat k) at
//   g = r>>4, rr = r&15, s = k>>5, kr = (k>>3)&3, off = k&7
//   idx = (((g*8 + s)*64) + kr*16 + rr)*8 + off
// One (g,s) fragment = 512 ushorts = 1KB, contiguous; wave reads it as
// lane*16B (the canonical conflict-free b128 fragment pattern).

__global__ __launch_bounds__(256) void prep_kernel(
    const float* __restrict__ sf, const float* __restrict__ tf,
    const int* __restrict__ lbl, const float* __restrict__ cw,
    unsigned short* __restrict__ sfb, unsigned short* __restrict__ tfb,
    float* __restrict__ x2s, float* __restrict__ x2t,
    float* __restrict__ wv, int ns)
{
    int row = blockIdx.x * 4 + (threadIdx.x >> 6);
    int t = threadIdx.x & 63;            // lane: handles k = 4t..4t+3
    bool is_src = row < ns;
    int r = is_src ? row : row - ns;
    const float* src = (is_src ? sf : tf) + (size_t)r * D;
    unsigned short* dstb = is_src ? sfb : tfb;

    float4 v = ((const float4*)src)[t];
    ushort4 u;
    u.x = f32_to_bf16(v.x); u.y = f32_to_bf16(v.y);
    u.z = f32_to_bf16(v.z); u.w = f32_to_bf16(v.w);

    int g = r >> 4, rr = r & 15;
    int k = t * 4;
    int s_ = k >> 5, kr = (k >> 3) & 3, off = k & 7;
    size_t idx = ((size_t)((g * 8 + s_) * 64) + kr * 16 + rr) * 8 + off;
    *(ushort4*)(dstb + idx) = u;

    float s = v.x * v.x + v.y * v.y + v.z * v.z + v.w * v.w;
    #pragma unroll
    for (int o = 32; o; o >>= 1) s += __shfl_xor(s, o);

    if (t == 0) {
        if (is_src) { wv[r] = cw[lbl[r]]; x2s[r] = s; }
        else        { x2t[r] = s; }
    }
}

static __device__ __forceinline__ void gload_lds16(const unsigned short* g,
                                                   unsigned short* l) {
    __builtin_amdgcn_global_load_lds(
        (const __attribute__((address_space(1))) void*)g,
        (__attribute__((address_space(3))) void*)l, 16, 0, 0);
}

// Fused gram kernel. Grid = tri(ti_s) + tri(ti_t) + ti_s*ti_t blocks.
//   mode 0: Kss weighted, symmetric, diag override
//   mode 1: Ktt plain sum, symmetric, diag override
//   mode 2: Kst row-weighted, full, no diag
// Block 256 thr = 4 waves (2x2), tile 128x128, wave tile 64x64.
// LDS: 2 buf x 32 units x 1KB (A units 0..15 = g*2+sl, B units 16..31).
__global__ __launch_bounds__(256, 2) void gram_kernel(
    const unsigned short* __restrict__ sfb, const unsigned short* __restrict__ tfb,
    const float* __restrict__ x2s, const float* __restrict__ x2t,
    const float* __restrict__ wv, float* __restrict__ bout,
    int ti_s, int ti_t)
{
    int tri_s = ti_s * (ti_s + 1) / 2;
    int tri_t = ti_t * (ti_t + 1) / 2;
    int blk = blockIdx.x;

    int mode, bi, bj;
    const unsigned short *X, *Y;
    const float *x2xp, *x2yp;
    if (blk < tri_s + tri_t) {
        int T, idx;
        if (blk < tri_s) { mode = 0; idx = blk; T = ti_s; X = sfb; Y = sfb; x2xp = x2s; x2yp = x2s; }
        else { mode = 1; idx = blk - tri_s; T = ti_t; X = tfb; Y = tfb; x2xp = x2t; x2yp = x2t; }
        bi = (int)((2.0f * T + 1.0f -
                    sqrtf((float)((2 * T + 1) * (2 * T + 1) - 8 * idx))) * 0.5f);
        if (bi < 0) bi = 0;
        if (bi > T - 1) bi = T - 1;
        int base = bi * (2 * T - bi + 1) / 2;
        while (base > idx) { --bi; base = bi * (2 * T - bi + 1) / 2; }
        while (idx >= base + (T - bi)) { base += (T - bi); ++bi; }
        bj = bi + (idx - base);
    } else {
        int idx = blk - tri_s - tri_t;
        mode = 2; bi = idx / ti_t; bj = idx % ti_t;
        X = sfb; Y = tfb; x2xp = x2s; x2yp = x2t;
    }
    float factor = (mode != 2 && bi != bj) ? 2.0f : 1.0f;

    __shared__ unsigned short lds[2][32][512];  // 64KB -> 2 blocks/CU

    int wid = threadIdx.x >> 6;
    int lane = threadIdx.x & 63;
    int wr = wid >> 1, wc = wid & 1;

    // group bases in fragment-major elements: group g occupies 8*512 elems
    const unsigned short* Abase = X + (size_t)(bi * 8) * 4096;
    const unsigned short* Bbase = Y + (size_t)(bj * 8) * 4096;

    // stage chunk c (K = c*64 .. c*64+63) into lds[buf]
    // unit u: A: u = g*2+sl (g 0..7, sl 0..1); B: u = 16 + g*2+sl
    // this wave stages units wid*8 .. wid*8+7
    auto STAGE = [&](int c, int buf) {
        #pragma unroll
        for (int j = 0; j < 8; ++j) {
            int u = wid * 8 + j;
            int isB = u >> 4;
            int g = (u & 15) >> 1;
            int sl = u & 1;
            const unsigned short* src =
                (isB ? Bbase : Abase) + ((size_t)g * 8 + c * 2 + sl) * 512 + lane * 8;
            gload_lds16(src, &lds[buf][u][0]);
        }
    };

    f32x4 acc[4][4] = {};

    STAGE(0, 0);
    __syncthreads();
    #pragma unroll
    for (int c = 0; c < 4; ++c) {
        if (c < 3) STAGE(c + 1, (c + 1) & 1);
        const int buf = c & 1;
        #pragma unroll
        for (int sl = 0; sl < 2; ++sl) {
            bf16x8 a[4], b[4];
            #pragma unroll
            for (int m = 0; m < 4; ++m)
                a[m] = *(const bf16x8*)&lds[buf][(wr * 4 + m) * 2 + sl][lane * 8];
            #pragma unroll
            for (int n = 0; n < 4; ++n)
                b[n] = *(const bf16x8*)&lds[buf][16 + (wc * 4 + n) * 2 + sl][lane * 8];
            #pragma unroll
            for (int m = 0; m < 4; ++m)
                #pragma unroll
                for (int n = 0; n < 4; ++n)
                    acc[m][n] = __builtin_amdgcn_mfma_f32_16x16x32_bf16(
                        a[m], b[n], acc[m][n], 0, 0, 0);
        }
        __syncthreads();
    }

    // Epilogue: C/D layout col = lane&15, row = (lane>>4)*4 + reg  [m89/m91]
    int R0 = bi * 128 + wr * 64;
    int C0 = bj * 128 + wc * 64;
    int crow = (lane >> 4) * 4;
    int ccol = lane & 15;
    float s = 0.0f;
    #pragma unroll
    for (int m = 0; m < 4; ++m) {
        #pragma unroll
        for (int r = 0; r < 4; ++r) {
            int gr = R0 + 16 * m + crow + r;
            float rx2 = x2xp[gr];
            float rw = (mode != 1) ? wv[gr] : 1.0f;
            #pragma unroll
            for (int n = 0; n < 4; ++n) {
                int gc = C0 + 16 * n + ccol;
                float S = acc[m][n][r];
                float sq = fmaxf(x2yp[gc] + rx2 - 2.0f * S, 0.0f);
                float K = __expf(-0.5f * sq);
                if (mode != 2 && gr == gc) K = 1.0f;  // exact diagonal
                float wf = (mode == 0) ? rw * wv[gc] : rw;
                s += wf * K;
            }
        }
    }
    s *= factor;
    #pragma unroll
    for (int o = 32; o; o >>= 1) s += __shfl_xor(s, o);

    __shared__ float bsum[4];
    if (lane == 0) bsum[wid] = s;
    __syncthreads();
    if (threadIdx.x == 0)
        bout[blk] = (bsum[0] + bsum[1]) + (bsum[2] + bsum[3]);
}

// Single-block final reduce: n = sum(wv), three mode sums from bout, combine.
__global__ __launch_bounds__(1024) void reduce_kernel(
    const float* __restrict__ wv, int ns,
    const float* __restrict__ bout, int tri_s, int tri_t, int nb,
    float* __restrict__ out, int nt)
{
    int tid = threadIdx.x;
    float n = 0.0f, a0 = 0.0f, a1 = 0.0f, a2 = 0.0f;
    for (int i = tid; i < ns; i += 1024) n += wv[i];
    for (int i = tid; i < nb; i += 1024) {
        float v = bout[i];
        if (i < tri_s) a0 += v;
        else if (i < tri_s + tri_t) a1 += v;
        else a2 += v;
    }
    #pragma unroll
    for (int o = 32; o; o >>= 1) {
        n  += __shfl_xor(n, o);
        a0 += __shfl_xor(a0, o);
        a1 += __shfl_xor(a1, o);
        a2 += __shfl_xor(a2, o);
    }
    __shared__ float ln[16], l0[16], l1[16], l2[16];
    int w = tid >> 6;
    if ((tid & 63) == 0) { ln[w] = n; l0[w] = a0; l1[w] = a1; l2[w] = a2; }
    __syncthreads();
    if (tid == 0) {
        float N = 0, A0 = 0, A1 = 0, A2 = 0;
        #pragma unroll
        for (int i = 0; i < 16; ++i) { N += ln[i]; A0 += l0[i]; A1 += l1[i]; A2 += l2[i]; }
        float fnt = (float)nt;
        out[0] = A0 / (N * N) + A1 / (fnt * fnt) - 2.0f * A2 / (N * fnt);
    }
}

extern "C" void kernel_launch(void* const* d_in, const int* in_sizes, int n_in,
                              void* d_out, int out_size, void* d_ws, size_t ws_size,
                              hipStream_t stream) {
    const float* sf = (const float*)d_in[0];
    const int* lbl = (const int*)d_in[1];
    const float* tf = (const float*)d_in[2];
    const float* cw = (const float*)d_in[3];
    float* out = (float*)d_out;

    int ns = in_sizes[1];
    int d = in_sizes[0] / ns;   // expect 256
    int nt = in_sizes[2] / d;

    char* p = (char*)d_ws;
    unsigned short* sfb = (unsigned short*)p;  p += (size_t)ns * d * sizeof(unsigned short);
    unsigned short* tfb = (unsigned short*)p;  p += (size_t)nt * d * sizeof(unsigned short);
    float* x2s = (float*)p;                    p += (size_t)ns * sizeof(float);
    float* x2t = (float*)p;                    p += (size_t)nt * sizeof(float);
    float* wv  = (float*)p;                    p += (size_t)ns * sizeof(float);
    float* bout = (float*)p;

    prep_kernel<<<(ns + nt) / 4, 256, 0, stream>>>(sf, tf, lbl, cw, sfb, tfb,
                                                   x2s, x2t, wv, ns);

    int ti_s = ns / 128, ti_t = nt / 128;
    int tri_s = ti_s * (ti_s + 1) / 2;
    int tri_t = ti_t * (ti_t + 1) / 2;
    int nblocks = tri_s + tri_t + ti_s * ti_t;
    gram_kernel<<<nblocks, 256, 0, stream>>>(sfb, tfb, x2s, x2t, wv, bout,
                                             ti_s, ti_t);

    reduce_kernel<<<1, 1024, 0, stream>>>(wv, ns, bout, tri_s, tri_t, nblocks,
                                          out, nt);
}